// Round 2
// baseline (763.316 us; speedup 1.0000x reference)
//
#include <hip/hip_runtime.h>

#define S_LEN 2048
#define HID 4096
#define NH 32
#define NKV 8
#define HD 128
#define QKVN 6144          // (32+16)*128
#define KOFF 4096          // q block size in qkv row
#define VOFF 5120          // q+k block size

typedef unsigned short ushort_t;
typedef unsigned int uint_t;
typedef __attribute__((ext_vector_type(8))) short short8;
typedef __attribute__((ext_vector_type(4))) short short4v;
typedef __attribute__((ext_vector_type(4))) float float4_t;

__device__ __forceinline__ float bf2f(ushort_t u) {
    return __uint_as_float(((uint_t)u) << 16);
}
__device__ __forceinline__ uint_t f2bf(float f) {
    uint_t u = __float_as_uint(f);
    u += 0x7fffu + ((u >> 16) & 1u);   // round-to-nearest-even
    return u >> 16;
}

// async global->LDS DMA: 16B per lane, LDS dest = wave-uniform base + lane*16
__device__ __forceinline__ void gload_lds16(const ushort_t* g, ushort_t* l) {
    __builtin_amdgcn_global_load_lds(
        (const __attribute__((address_space(1))) void*)g,
        (__attribute__((address_space(3))) void*)l, 16, 0, 0);
}

// --------------------------------------------------------- fp32 -> bf16 copy
__global__ void f32_to_bf16(const float* __restrict__ in,
                            ushort_t* __restrict__ out) {
    int i = blockIdx.x * 256 + threadIdx.x;
    out[i] = (ushort_t)f2bf(in[i]);
}

// --------------------------------------------- transpose + convert to bf16
// out[C][R] (bf16) = in[R][C] (fp32)
__global__ void transpose_f32_bf16(const float* __restrict__ in,
                                   ushort_t* __restrict__ out, int R, int C) {
    __shared__ float t[32][33];
    int c0 = blockIdx.x * 32, r0 = blockIdx.y * 32;
    int ci = threadIdx.x & 31, rb = threadIdx.x >> 5;   // rb in [0,8)
#pragma unroll
    for (int p = 0; p < 4; p++) {
        int ri = rb + p * 8;
        t[ri][ci] = in[(size_t)(r0 + ri) * C + c0 + ci];
    }
    __syncthreads();
#pragma unroll
    for (int p = 0; p < 4; p++) {
        int ri = rb + p * 8;
        out[(size_t)(c0 + ri) * R + r0 + ci] = (ushort_t)f2bf(t[ci][ri]);
    }
}

// ---------------------------------------------------------------- GEMM
// C[M][N] (fp32) = A[M][K] (bf16 row-major) * BT[N][K]^T (bf16 row-major)
// 128x128 block tile, BK=32, 4 waves, each wave 64x64 via 4x4 mfma 16x16x32.
// m97 structure: staging via global_load_lds dwordx4 (direct HBM->LDS DMA);
// LDS layout is linear in lane order (tid*16B + p*4096B), which equals
// As[r][kc] with r = tid/4 + p*64, kc = (tid%4)*8 -- same map as the frag
// reads expect. Two barriers per K-step (compiler drains vmcnt at barrier).
__global__ __launch_bounds__(256, 2)
void gemm_bf16(const ushort_t* __restrict__ A, const ushort_t* __restrict__ BT,
               float* __restrict__ Cout, int M, int N, int K) {
    __shared__ __attribute__((aligned(16))) ushort_t As[128 * 32];
    __shared__ __attribute__((aligned(16))) ushort_t Bs[128 * 32];
    const int tid  = threadIdx.x;
    const int wave = tid >> 6;
    const int lane = tid & 63;
    const int quad = lane >> 4;
    const int l16  = lane & 15;
    const int m0 = blockIdx.y * 128;
    const int n0 = blockIdx.x * 128;
    const int wm = (wave & 1) * 64;
    const int wn = (wave >> 1) * 64;

    // per-lane staging addresses (loop-invariant bases)
    const int r0 = tid >> 2;            // row handled by this lane (p=0)
    const int kc = (tid & 3) * 8;       // k-element offset within the row
    const ushort_t* gA0 = A  + (size_t)(m0 + r0)      * K + kc;
    const ushort_t* gA1 = A  + (size_t)(m0 + r0 + 64) * K + kc;
    const ushort_t* gB0 = BT + (size_t)(n0 + r0)      * K + kc;
    const ushort_t* gB1 = BT + (size_t)(n0 + r0 + 64) * K + kc;
    ushort_t* lA0 = &As[r0 * 32 + kc];          // byte off = tid*16
    ushort_t* lA1 = lA0 + 64 * 32;              // + 4096 B
    ushort_t* lB0 = &Bs[r0 * 32 + kc];
    ushort_t* lB1 = lB0 + 64 * 32;

    float4_t acc[4][4] = {};

    for (int k0 = 0; k0 < K; k0 += 32) {
        gload_lds16(gA0 + k0, lA0);
        gload_lds16(gA1 + k0, lA1);
        gload_lds16(gB0 + k0, lB0);
        gload_lds16(gB1 + k0, lB1);
        __syncthreads();

        short8 af[4], bfr[4];
#pragma unroll
        for (int i = 0; i < 4; i++)
            af[i] = *(const short8*)(&As[(wm + i * 16 + l16) * 32 + quad * 8]);
#pragma unroll
        for (int j = 0; j < 4; j++)
            bfr[j] = *(const short8*)(&Bs[(wn + j * 16 + l16) * 32 + quad * 8]);
#pragma unroll
        for (int i = 0; i < 4; i++)
#pragma unroll
            for (int j = 0; j < 4; j++)
                acc[i][j] = __builtin_amdgcn_mfma_f32_16x16x32_bf16(
                    af[i], bfr[j], acc[i][j], 0, 0, 0);
        __syncthreads();
    }

#pragma unroll
    for (int i = 0; i < 4; i++)
#pragma unroll
        for (int j = 0; j < 4; j++)
#pragma unroll
            for (int r = 0; r < 4; r++) {
                int row = m0 + wm + i * 16 + quad * 4 + r;
                int col = n0 + wn + j * 16 + l16;
                Cout[(size_t)row * N + col] = acc[i][j][r];
            }
}

// ------------------------------------------------ prep Q (RoPE + scale + bf16)
// Qb[h][s][d] = rope(qkv[s][h*128+d]) * (scale * log2(e))
// Score*log2e is then exactly what exp2 needs in flash_attn.
#define QSC 0.12753102543918255f   // 128^-0.5 * log2(e)
__global__ void prep_q(const float* __restrict__ qkv, ushort_t* __restrict__ Qb) {
    int idx = blockIdx.x * 256 + threadIdx.x;   // h*S*HD + s*HD + d
    int d = idx & 127;
    int s = (idx >> 7) & 2047;
    int h = idx >> 18;
    const float* row = qkv + (size_t)s * QKVN + h * HD;
    float v;
    if (d < 64) {
        int i = d & 31;
        float invf = exp2f(-(float)i * (13.287712379549449f / 32.0f));
        float fr = (float)s * invf;
        float c, sn;
        sincosf(fr, &sn, &c);
        float x1 = row[i], x2 = row[i + 32];
        v = (d < 32) ? (x1 * c - x2 * sn) : (x2 * c + x1 * sn);
    } else {
        v = row[d];
    }
    Qb[idx] = (ushort_t)f2bf(v * QSC);
}

// ------------------------------------------------ prep K (RoPE + bf16 pack)
// Kb[hk][t][d] = rope(qkv[t][KOFF + hk*128 + d])
__global__ void prep_k(const float* __restrict__ qkv, ushort_t* __restrict__ Kb) {
    int idx = blockIdx.x * 256 + threadIdx.x;
    int d = idx & 127;
    int t = (idx >> 7) & 2047;
    int hk = idx >> 18;
    const float* row = qkv + (size_t)t * QKVN + KOFF + hk * HD;
    float v;
    if (d < 64) {
        int i = d & 31;
        float invf = exp2f(-(float)i * (13.287712379549449f / 32.0f));
        float fr = (float)t * invf;
        float c, sn;
        sincosf(fr, &sn, &c);
        float x1 = row[i], x2 = row[i + 32];
        v = (d < 32) ? (x1 * c - x2 * sn) : (x2 * c + x1 * sn);
    } else {
        v = row[d];
    }
    Kb[idx] = (ushort_t)f2bf(v);
}

// ------------------------------------------------ prep V (transpose to [d][t])
// Vt[hk][d][t] = qkv[t][VOFF + hk*128 + d]
__global__ void prep_v(const float* __restrict__ qkv, ushort_t* __restrict__ Vt) {
    __shared__ float tile[32][33];
    int hk = blockIdx.z;
    int t0 = blockIdx.x * 32, d0 = blockIdx.y * 32;
    int ci = threadIdx.x & 31, rb = threadIdx.x >> 5;
#pragma unroll
    for (int p = 0; p < 4; p++) {
        int tr = rb + p * 8;
        tile[tr][ci] = qkv[(size_t)(t0 + tr) * QKVN + VOFF + hk * HD + d0 + ci];
    }
    __syncthreads();
#pragma unroll
    for (int p = 0; p < 4; p++) {
        int dr = rb + p * 8;
        Vt[((size_t)hk * HD + d0 + dr) * S_LEN + t0 + ci] = (ushort_t)f2bf(tile[ci][dr]);
    }
}

// ---------------------------------------------------------- flash attention
// S^T = K·Q^T (Q pre-scaled by scale*log2e), P = 2^S (NO max subtraction:
// scores bounded ~19 nats, diagonal guarantees l>=1), O^T = V^T·P^T.
// One wave = 16 q-rows; qt = bx + 32*wave balances heavy/light waves per block.
// Deferred l-reduction; peeled masked diagonal tile; packed-bf16 shuffles.
// mfma_f32_16x16x32_bf16 layouts: A[m=l16][k=quad*8+j], B[k=quad*8+j][n=l16],
// C/D row=quad*4+reg, col=l16.
//
// v2: latency fix. VGPR=56 build serialized the 16 per-iter global loads
// (zero reg headroom -> load/wait/use one at a time, ~5k cyc/iter).
// Now: K fragments double-buffered across iterations (K(t0+32) issued at top
// of iter t0, consumed next iter -> full latency hidden); V loads hoisted
// ahead of their PV use (first half above QK, second half above shuffles).
// Costs ~100 extra VGPRs (-> ~3 waves/SIMD); buys ~10x fewer exposed stalls.
__global__ __launch_bounds__(256, 2)
void flash_attn(const ushort_t* __restrict__ Qb, const ushort_t* __restrict__ Kb,
                const ushort_t* __restrict__ Vt, ushort_t* __restrict__ attn) {
    const int h    = blockIdx.y;
    const int hk   = h >> 2;                 // GQA: 4 q-heads per kv-head
    const int wave = threadIdx.x >> 6;
    const int lane = threadIdx.x & 63;
    const int quad = lane >> 4;
    const int l16  = lane & 15;
    const int qt   = blockIdx.x + 32 * wave; // 0..127
    const int qw   = qt * 16;                // first q row of this wave

    const ushort_t* Qh = Qb + (size_t)h  * S_LEN * HD;
    const ushort_t* Kh = Kb + (size_t)hk * S_LEN * HD;
    const ushort_t* Vh = Vt + (size_t)hk * HD * S_LEN;

    // Q fragments (loop-invariant): B[k=d][n=q], contiguous 16B loads
    short8 qf[4];
#pragma unroll
    for (int c = 0; c < 4; c++)
        qf[c] = *(const short8*)(Qh + (size_t)(qw + l16) * HD + c * 32 + quad * 8);

    float4_t oacc[8] = {};                   // O^T: 8 d-tiles of 16, col=q=l16
    float lsum = 0.f;                        // per-lane partial softmax denom
    const int s0 = (((quad * 2)     & 3) << 4) | l16;   // shuffle src lanes
    const int s1 = (((quad * 2 + 1) & 3) << 4) | l16;

    const int T0 = qw & ~31;                 // start of the masked diagonal tile

    // per-lane K base pointers (row t0+l16 / t0+16+l16, col quad*8)
    const ushort_t* kpA = Kh + (size_t)l16 * HD + quad * 8;
    const ushort_t* kpB = kpA + 16 * HD;

    // preload K tile for t0 = 0
    short8 kcA[4], kcB[4];
#pragma unroll
    for (int c = 0; c < 4; c++) {
        kcA[c] = *(const short8*)(kpA + c * 32);
        kcB[c] = *(const short8*)(kpB + c * 32);
    }

#pragma unroll 1
    for (int t0 = 0; t0 <= T0; t0 += 32) {
        // V loads, first half: consumed ~350 cyc later in PV
        short8 vf[8];
#pragma unroll
        for (int dt = 0; dt < 4; dt++)
            vf[dt] = *(const short8*)(Vh + (size_t)(dt * 16 + l16) * S_LEN + t0 + quad * 8);

        // prefetch NEXT K tile; lands during this iter's compute
        const bool pf = (t0 < T0);
        short8 knA[4], knB[4];
        if (pf) {
            const ushort_t* nA = kpA + (size_t)(t0 + 32) * HD;
            const ushort_t* nB = nA + 16 * HD;
#pragma unroll
            for (int c = 0; c < 4; c++) {
                knA[c] = *(const short8*)(nA + c * 32);
                knB[c] = *(const short8*)(nB + c * 32);
            }
        }

        // two S^T tiles from the CURRENT (prefetched last iter) K frags
        float4_t stA = {}, stB = {};
#pragma unroll
        for (int c = 0; c < 4; c++) {
            stA = __builtin_amdgcn_mfma_f32_16x16x32_bf16(kcA[c], qf[c], stA, 0, 0, 0);
            stB = __builtin_amdgcn_mfma_f32_16x16x32_bf16(kcB[c], qf[c], stB, 0, 0, 0);
        }

        // P = 2^st (st already includes scale*log2e); mask only diagonal tile
        const bool maskT = (t0 == T0);
        float pA[4], pB[4];
#pragma unroll
        for (int r = 0; r < 4; r++) {
            float eA = exp2f(stA[r]);
            float eB = exp2f(stB[r]);
            if (maskT) {
                int tA = t0 + quad * 4 + r;
                eA = (tA      <= qw + l16) ? eA : 0.f;
                eB = (tA + 16 <= qw + l16) ? eB : 0.f;
            }
            pA[r] = eA; pB[r] = eB;
            lsum += eA + eB;
        }

        // V loads, second half (ahead of the shuffles that gate PV)
#pragma unroll
        for (int dt = 4; dt < 8; dt++)
            vf[dt] = *(const short8*)(Vh + (size_t)(dt * 16 + l16) * S_LEN + t0 + quad * 8);

        // P^T C-layout -> K=32 B-frag via packed-bf16 shuffles.
        // pb[j] = P^T[t0+quad*8+j][q=l16]; regs 0..3 from src lane s0,
        // regs 4..7 from s1; tile A for quads 0-1, tile B for quads 2-3.
        uint_t a01 = f2bf(pA[0]) | (f2bf(pA[1]) << 16);
        uint_t a23 = f2bf(pA[2]) | (f2bf(pA[3]) << 16);
        uint_t b01 = f2bf(pB[0]) | (f2bf(pB[1]) << 16);
        uint_t b23 = f2bf(pB[2]) | (f2bf(pB[3]) << 16);
        uint_t A01s0 = (uint_t)__shfl((int)a01, s0);
        uint_t A23s0 = (uint_t)__shfl((int)a23, s0);
        uint_t B01s0 = (uint_t)__shfl((int)b01, s0);
        uint_t B23s0 = (uint_t)__shfl((int)b23, s0);
        uint_t A01s1 = (uint_t)__shfl((int)a01, s1);
        uint_t A23s1 = (uint_t)__shfl((int)a23, s1);
        uint_t B01s1 = (uint_t)__shfl((int)b01, s1);
        uint_t B23s1 = (uint_t)__shfl((int)b23, s1);
        uint_t w[4];
        w[0] = quad < 2 ? A01s0 : B01s0;
        w[1] = quad < 2 ? A23s0 : B23s0;
        w[2] = quad < 2 ? A01s1 : B01s1;
        w[3] = quad < 2 ? A23s1 : B23s1;
        short8 pb;
        __builtin_memcpy(&pb, w, 16);

        // O^T += V^T · P^T : A = V-frag (loaded above, latency already hidden)
#pragma unroll
        for (int dt = 0; dt < 8; dt++)
            oacc[dt] = __builtin_amdgcn_mfma_f32_16x16x32_bf16(vf[dt], pb, oacc[dt], 0, 0, 0);

        // rotate K double-buffer
        if (pf) {
#pragma unroll
            for (int c = 0; c < 4; c++) { kcA[c] = knA[c]; kcB[c] = knB[c]; }
        }
    }

    // epilogue: reduce l across quads (lane bits 4,5), normalize, store.
    lsum += __shfl_xor(lsum, 16);
    lsum += __shfl_xor(lsum, 32);
    float invl = 1.f / lsum;
    ushort_t* orow = attn + (size_t)(qw + l16) * (NH * HD) + h * HD;
#pragma unroll
    for (int dt = 0; dt < 8; dt++) {
        short4v wv;
#pragma unroll
        for (int r = 0; r < 4; r++)
            wv[r] = (short)f2bf(oacc[dt][r] * invl);
        *(short4v*)(orow + dt * 16 + quad * 4) = wv;
    }
}

// ---------------------------------------------------------------- launch
extern "C" void kernel_launch(void* const* d_in, const int* in_sizes, int n_in,
                              void* d_out, int out_size, void* d_ws, size_t ws_size,
                              hipStream_t stream) {
    const float* hidden = (const float*)d_in[0];   // fp32 [2048][4096]
    const float* Wqkv   = (const float*)d_in[1];   // fp32 [4096][6144]
    const float* Wo     = (const float*)d_in[2];   // fp32 [4096][4096]
    // d_in[3] positions == arange(SEQ); position index == s, so unused.
    float* out = (float*)d_out;                    // fp32 [2048][4096]

    char* ws = (char*)d_ws;
    float*    qkv   = (float*)   (ws);                   // 50,331,648 B fp32
    ushort_t* attnB = (ushort_t*)(ws);                   // aliases qkv (qkv dead after preps)
    ushort_t* hidB  = (ushort_t*)(ws + 50331648);        // 16,777,216 B bf16
    ushort_t* Qb    = hidB;                              // aliases hidB (dead after GEMM1)
    ushort_t* WqkvT = (ushort_t*)(ws + 67108864);        // 50,331,648 B bf16
    ushort_t* WoT   = (ushort_t*)(ws + 117440512);       // 33,554,432 B bf16
    ushort_t* Kb    = (ushort_t*)(ws + 150994944);       //  4,194,304 B bf16
    ushort_t* Vt    = (ushort_t*)(ws + 155189248);       //  4,194,304 B bf16

    f32_to_bf16<<<(S_LEN * HID) / 256, 256, 0, stream>>>(hidden, hidB);
    transpose_f32_bf16<<<dim3(QKVN / 32, HID / 32), 256, 0, stream>>>(Wqkv, WqkvT, HID, QKVN);
    transpose_f32_bf16<<<dim3(HID / 32, HID / 32), 256, 0, stream>>>(Wo, WoT, HID, HID);

    gemm_bf16<<<dim3(QKVN / 128, S_LEN / 128), 256, 0, stream>>>(
        hidB, WqkvT, qkv, S_LEN, QKVN, HID);

    prep_q<<<(NH  * S_LEN * HD) / 256, 256, 0, stream>>>(qkv, Qb);
    prep_k<<<(NKV * S_LEN * HD) / 256, 256, 0, stream>>>(qkv, Kb);
    prep_v<<<dim3(S_LEN / 32, HD / 32, NKV), 256, 0, stream>>>(qkv, Vt);

    flash_attn<<<dim3(32, NH), 256, 0, stream>>>(Qb, Kb, Vt, attnB);

    gemm_bf16<<<dim3(HID / 128, S_LEN / 128), 256, 0, stream>>>(
        attnB, WoT, out, S_LEN, HID, HID);
}

// Round 3
// 590.118 us; speedup vs baseline: 1.2935x; 1.2935x over previous
//
#include <hip/hip_runtime.h>

#define S_LEN 2048
#define HID 4096
#define NH 32
#define NKV 8
#define HD 128
#define QKVN 6144          // (32+16)*128
#define KOFF 4096          // q block size in qkv row
#define VOFF 5120          // q+k block size

typedef unsigned short ushort_t;
typedef unsigned int uint_t;
typedef __attribute__((ext_vector_type(8))) short short8;
typedef __attribute__((ext_vector_type(4))) short short4v;
typedef __attribute__((ext_vector_type(4))) float float4_t;

__device__ __forceinline__ float bf2f(ushort_t u) {
    return __uint_as_float(((uint_t)u) << 16);
}
__device__ __forceinline__ uint_t f2bf(float f) {
    uint_t u = __float_as_uint(f);
    u += 0x7fffu + ((u >> 16) & 1u);   // round-to-nearest-even
    return u >> 16;
}

// async global->LDS DMA: 16B per lane, LDS dest = wave-uniform base + lane*16
__device__ __forceinline__ void gload_lds16(const ushort_t* g, ushort_t* l) {
    __builtin_amdgcn_global_load_lds(
        (const __attribute__((address_space(1))) void*)g,
        (__attribute__((address_space(3))) void*)l, 16, 0, 0);
}

// --------------------------------------------------------- fp32 -> bf16 copy
__global__ void f32_to_bf16(const float* __restrict__ in,
                            ushort_t* __restrict__ out) {
    int i = blockIdx.x * 256 + threadIdx.x;
    out[i] = (ushort_t)f2bf(in[i]);
}

// --------------------------------------------- transpose + convert to bf16
// out[C][R] (bf16) = in[R][C] (fp32)
__global__ void transpose_f32_bf16(const float* __restrict__ in,
                                   ushort_t* __restrict__ out, int R, int C) {
    __shared__ float t[32][33];
    int c0 = blockIdx.x * 32, r0 = blockIdx.y * 32;
    int ci = threadIdx.x & 31, rb = threadIdx.x >> 5;   // rb in [0,8)
#pragma unroll
    for (int p = 0; p < 4; p++) {
        int ri = rb + p * 8;
        t[ri][ci] = in[(size_t)(r0 + ri) * C + c0 + ci];
    }
    __syncthreads();
#pragma unroll
    for (int p = 0; p < 4; p++) {
        int ri = rb + p * 8;
        out[(size_t)(c0 + ri) * R + r0 + ci] = (ushort_t)f2bf(t[ci][ri]);
    }
}

// ---------------------------------------------------------------- GEMM
// C[M][N] (fp32) = A[M][K] (bf16 row-major) * BT[N][K]^T (bf16 row-major)
// 128x128 block tile, BK=32, 4 waves, each wave 64x64 via 4x4 mfma 16x16x32.
// m97 structure: staging via global_load_lds dwordx4 (direct HBM->LDS DMA).
__global__ __launch_bounds__(256, 2)
void gemm_bf16(const ushort_t* __restrict__ A, const ushort_t* __restrict__ BT,
               float* __restrict__ Cout, int M, int N, int K) {
    __shared__ __attribute__((aligned(16))) ushort_t As[128 * 32];
    __shared__ __attribute__((aligned(16))) ushort_t Bs[128 * 32];
    const int tid  = threadIdx.x;
    const int wave = tid >> 6;
    const int lane = tid & 63;
    const int quad = lane >> 4;
    const int l16  = lane & 15;
    const int m0 = blockIdx.y * 128;
    const int n0 = blockIdx.x * 128;
    const int wm = (wave & 1) * 64;
    const int wn = (wave >> 1) * 64;

    // per-lane staging addresses (loop-invariant bases)
    const int r0 = tid >> 2;            // row handled by this lane (p=0)
    const int kc = (tid & 3) * 8;       // k-element offset within the row
    const ushort_t* gA0 = A  + (size_t)(m0 + r0)      * K + kc;
    const ushort_t* gA1 = A  + (size_t)(m0 + r0 + 64) * K + kc;
    const ushort_t* gB0 = BT + (size_t)(n0 + r0)      * K + kc;
    const ushort_t* gB1 = BT + (size_t)(n0 + r0 + 64) * K + kc;
    ushort_t* lA0 = &As[r0 * 32 + kc];          // byte off = tid*16
    ushort_t* lA1 = lA0 + 64 * 32;              // + 4096 B
    ushort_t* lB0 = &Bs[r0 * 32 + kc];
    ushort_t* lB1 = lB0 + 64 * 32;

    float4_t acc[4][4] = {};

    for (int k0 = 0; k0 < K; k0 += 32) {
        gload_lds16(gA0 + k0, lA0);
        gload_lds16(gA1 + k0, lA1);
        gload_lds16(gB0 + k0, lB0);
        gload_lds16(gB1 + k0, lB1);
        __syncthreads();

        short8 af[4], bfr[4];
#pragma unroll
        for (int i = 0; i < 4; i++)
            af[i] = *(const short8*)(&As[(wm + i * 16 + l16) * 32 + quad * 8]);
#pragma unroll
        for (int j = 0; j < 4; j++)
            bfr[j] = *(const short8*)(&Bs[(wn + j * 16 + l16) * 32 + quad * 8]);
#pragma unroll
        for (int i = 0; i < 4; i++)
#pragma unroll
            for (int j = 0; j < 4; j++)
                acc[i][j] = __builtin_amdgcn_mfma_f32_16x16x32_bf16(
                    af[i], bfr[j], acc[i][j], 0, 0, 0);
        __syncthreads();
    }

#pragma unroll
    for (int i = 0; i < 4; i++)
#pragma unroll
        for (int j = 0; j < 4; j++)
#pragma unroll
            for (int r = 0; r < 4; r++) {
                int row = m0 + wm + i * 16 + quad * 4 + r;
                int col = n0 + wn + j * 16 + l16;
                Cout[(size_t)row * N + col] = acc[i][j][r];
            }
}

// ------------------------------------------------ prep Q (RoPE + scale + bf16)
#define QSC 0.12753102543918255f   // 128^-0.5 * log2(e)
__global__ void prep_q(const float* __restrict__ qkv, ushort_t* __restrict__ Qb) {
    int idx = blockIdx.x * 256 + threadIdx.x;   // h*S*HD + s*HD + d
    int d = idx & 127;
    int s = (idx >> 7) & 2047;
    int h = idx >> 18;
    const float* row = qkv + (size_t)s * QKVN + h * HD;
    float v;
    if (d < 64) {
        int i = d & 31;
        float invf = exp2f(-(float)i * (13.287712379549449f / 32.0f));
        float fr = (float)s * invf;
        float c, sn;
        sincosf(fr, &sn, &c);
        float x1 = row[i], x2 = row[i + 32];
        v = (d < 32) ? (x1 * c - x2 * sn) : (x2 * c + x1 * sn);
    } else {
        v = row[d];
    }
    Qb[idx] = (ushort_t)f2bf(v * QSC);
}

// ------------------------------------------------ prep K (RoPE + bf16 pack)
__global__ void prep_k(const float* __restrict__ qkv, ushort_t* __restrict__ Kb) {
    int idx = blockIdx.x * 256 + threadIdx.x;
    int d = idx & 127;
    int t = (idx >> 7) & 2047;
    int hk = idx >> 18;
    const float* row = qkv + (size_t)t * QKVN + KOFF + hk * HD;
    float v;
    if (d < 64) {
        int i = d & 31;
        float invf = exp2f(-(float)i * (13.287712379549449f / 32.0f));
        float fr = (float)t * invf;
        float c, sn;
        sincosf(fr, &sn, &c);
        float x1 = row[i], x2 = row[i + 32];
        v = (d < 32) ? (x1 * c - x2 * sn) : (x2 * c + x1 * sn);
    } else {
        v = row[d];
    }
    Kb[idx] = (ushort_t)f2bf(v);
}

// ------------------------------------------------ prep V (transpose to [d][t])
__global__ void prep_v(const float* __restrict__ qkv, ushort_t* __restrict__ Vt) {
    __shared__ float tile[32][33];
    int hk = blockIdx.z;
    int t0 = blockIdx.x * 32, d0 = blockIdx.y * 32;
    int ci = threadIdx.x & 31, rb = threadIdx.x >> 5;
#pragma unroll
    for (int p = 0; p < 4; p++) {
        int tr = rb + p * 8;
        tile[tr][ci] = qkv[(size_t)(t0 + tr) * QKVN + VOFF + hk * HD + d0 + ci];
    }
    __syncthreads();
#pragma unroll
    for (int p = 0; p < 4; p++) {
        int dr = rb + p * 8;
        Vt[((size_t)hk * HD + d0 + dr) * S_LEN + t0 + ci] = (ushort_t)f2bf(tile[ci][dr]);
    }
}

// ---------------------------------------------------------- flash attention
// v3: block-cooperative LDS staging. The 4 waves of a block now cover
// ADJACENT q-tiles (qt = 4*bx' + wave, bx' = 31-blockIdx.x so heavy blocks
// dispatch first) and share one kv-head, so K/V tiles are staged ONCE per
// block via global_load_lds (zero VGPRs, HW-tracked vmcnt -> the compiler
// cannot un-pipeline it), double-buffered, one barrier per 32-step.
//   K LDS tile [32][128] would be a 16-way bank conflict on ds_read_b128
//   (G4: row-major at D=128) -> XOR swizzle, applied BOTH sides (rule #21):
//   linear LDS dest + inverse-swizzled GLOBAL source + swizzled read.
//   V LDS tile [128][32] (64B rows) has the standard b128 profile, no swizzle.
// Waves differ in T0 by at most one tile; tiles past a wave's T0 are fully
// masked by the causal select (exp stays finite, contributes 0).
__global__ __launch_bounds__(256, 4)
void flash_attn(const ushort_t* __restrict__ Qb, const ushort_t* __restrict__ Kb,
                const ushort_t* __restrict__ Vt, ushort_t* __restrict__ attn) {
    __shared__ __attribute__((aligned(16))) ushort_t Ks[2][32 * 128];
    __shared__ __attribute__((aligned(16))) ushort_t Vs[2][128 * 32];

    const int h    = blockIdx.y;
    const int hk   = h >> 2;                 // GQA: 4 q-heads per kv-head
    const int tid  = threadIdx.x;
    const int wave = tid >> 6;
    const int lane = tid & 63;
    const int quad = lane >> 4;
    const int l16  = lane & 15;
    const int bx   = 31 - (int)blockIdx.x;   // heavy blocks first
    const int qt   = 4 * bx + wave;          // 0..127, adjacent within block
    const int qw   = qt * 16;                // first q row of this wave

    const ushort_t* Qh = Qb + (size_t)h  * S_LEN * HD;
    const ushort_t* Kh = Kb + (size_t)hk * S_LEN * HD;
    const ushort_t* Vh = Vt + (size_t)hk * HD * S_LEN;

    // ---- staging maps (loop-invariant). LDS slot = tid*16B + p*4096B ----
    // K: row r = tid/16 (+16 for p=1), granule g = tid%16; source granule
    //    g ^ (r&7) pre-applies the read-side XOR swizzle.
    const int krow = tid >> 4;
    const int ksrc = ((tid & 15) ^ (krow & 7)) << 3;   // shorts
    const ushort_t* gK0 = Kh + (size_t)krow * HD + ksrc;
    const ushort_t* gK1 = Kh + (size_t)(krow + 16) * HD + ksrc;
    // V: d-row tid/4 (+64 for p=1), t-granule tid%4
    const int vrow = tid >> 2;
    const int vtb  = (tid & 3) << 3;                   // shorts
    const ushort_t* gV0 = Vh + (size_t)vrow * S_LEN + vtb;
    const ushort_t* gV1 = Vh + (size_t)(vrow + 64) * S_LEN + vtb;

    ushort_t* lK = &Ks[0][tid * 8];          // byte off = tid*16
    ushort_t* lV = &Vs[0][tid * 8];

#define STAGE(buf, t0)                                                        \
    do {                                                                      \
        gload_lds16(gK0 + (size_t)(t0) * HD, lK + (buf) * (32 * 128));        \
        gload_lds16(gK1 + (size_t)(t0) * HD, lK + (buf) * (32 * 128) + 2048); \
        gload_lds16(gV0 + (t0),              lV + (buf) * (128 * 32));        \
        gload_lds16(gV1 + (t0),              lV + (buf) * (128 * 32) + 2048); \
    } while (0)

    // Q fragments (loop-invariant): B[k=d][n=q], contiguous 16B loads
    short8 qf[4];
#pragma unroll
    for (int c = 0; c < 4; c++)
        qf[c] = *(const short8*)(Qh + (size_t)(qw + l16) * HD + c * 32 + quad * 8);

    float4_t oacc[8] = {};                   // O^T: 8 d-tiles of 16, col=q=l16
    float lsum = 0.f;                        // per-lane partial softmax denom
    const int s0 = (((quad * 2)     & 3) << 4) | l16;   // shuffle src lanes
    const int s1 = (((quad * 2 + 1) & 3) << 4) | l16;

    const int T0w   = qw & ~31;              // this wave's masked-tile start
    const int T0max = (16 * (4 * bx + 3)) & ~31;   // block loop bound
    const int kxor  = (l16 & 7) << 3;        // read-side XOR (shorts)

    STAGE(0, 0);
    __syncthreads();                         // drains vmcnt -> buf0 ready

#pragma unroll 1
    for (int t0 = 0; t0 <= T0max; t0 += 32) {
        const int cur = (t0 >> 5) & 1;
        if (t0 + 32 <= T0max) STAGE(cur ^ 1, t0 + 32);   // async, lands at barrier

        const ushort_t* Kbuf = Ks[cur];
        const ushort_t* Vbuf = Vs[cur];

        // two S^T tiles: stA covers t0..t0+15, stB covers t0+16..t0+31
        float4_t stA = {}, stB = {};
#pragma unroll
        for (int c = 0; c < 4; c++) {
            short8 kfA = *(const short8*)(Kbuf + l16 * 128 +
                                          ((c * 32 + quad * 8) ^ kxor));
            short8 kfB = *(const short8*)(Kbuf + (16 + l16) * 128 +
                                          ((c * 32 + quad * 8) ^ kxor));
            stA = __builtin_amdgcn_mfma_f32_16x16x32_bf16(kfA, qf[c], stA, 0, 0, 0);
            stB = __builtin_amdgcn_mfma_f32_16x16x32_bf16(kfB, qf[c], stB, 0, 0, 0);
        }

        // P = 2^st (st already includes scale*log2e); mask at/past diagonal
        const bool maskT = (t0 >= T0w);
        float pA[4], pB[4];
#pragma unroll
        for (int r = 0; r < 4; r++) {
            float eA = exp2f(stA[r]);
            float eB = exp2f(stB[r]);
            if (maskT) {
                int tA = t0 + quad * 4 + r;
                eA = (tA      <= qw + l16) ? eA : 0.f;
                eB = (tA + 16 <= qw + l16) ? eB : 0.f;
            }
            pA[r] = eA; pB[r] = eB;
            lsum += eA + eB;
        }

        // P^T C-layout -> K=32 B-frag via packed-bf16 shuffles.
        uint_t a01 = f2bf(pA[0]) | (f2bf(pA[1]) << 16);
        uint_t a23 = f2bf(pA[2]) | (f2bf(pA[3]) << 16);
        uint_t b01 = f2bf(pB[0]) | (f2bf(pB[1]) << 16);
        uint_t b23 = f2bf(pB[2]) | (f2bf(pB[3]) << 16);
        uint_t A01s0 = (uint_t)__shfl((int)a01, s0);
        uint_t A23s0 = (uint_t)__shfl((int)a23, s0);
        uint_t B01s0 = (uint_t)__shfl((int)b01, s0);
        uint_t B23s0 = (uint_t)__shfl((int)b23, s0);
        uint_t A01s1 = (uint_t)__shfl((int)a01, s1);
        uint_t A23s1 = (uint_t)__shfl((int)a23, s1);
        uint_t B01s1 = (uint_t)__shfl((int)b01, s1);
        uint_t B23s1 = (uint_t)__shfl((int)b23, s1);
        uint_t w[4];
        w[0] = quad < 2 ? A01s0 : B01s0;
        w[1] = quad < 2 ? A23s0 : B23s0;
        w[2] = quad < 2 ? A01s1 : B01s1;
        w[3] = quad < 2 ? A23s1 : B23s1;
        short8 pb;
        __builtin_memcpy(&pb, w, 16);

        // O^T += V^T · P^T : A = V-frag from LDS (b128, standard profile)
#pragma unroll
        for (int dt = 0; dt < 8; dt++) {
            short8 vf = *(const short8*)(Vbuf + (dt * 16 + l16) * 32 + quad * 8);
            oacc[dt] = __builtin_amdgcn_mfma_f32_16x16x32_bf16(vf, pb, oacc[dt], 0, 0, 0);
        }

        __syncthreads();   // drains staging vmcnt; protects buf reuse
    }
#undef STAGE

    // epilogue: reduce l across quads (lane bits 4,5), normalize, store.
    lsum += __shfl_xor(lsum, 16);
    lsum += __shfl_xor(lsum, 32);
    float invl = 1.f / lsum;
    ushort_t* orow = attn + (size_t)(qw + l16) * (NH * HD) + h * HD;
#pragma unroll
    for (int dt = 0; dt < 8; dt++) {
        short4v wv;
#pragma unroll
        for (int r = 0; r < 4; r++)
            wv[r] = (short)f2bf(oacc[dt][r] * invl);
        *(short4v*)(orow + dt * 16 + quad * 4) = wv;
    }
}

// ---------------------------------------------------------------- launch
extern "C" void kernel_launch(void* const* d_in, const int* in_sizes, int n_in,
                              void* d_out, int out_size, void* d_ws, size_t ws_size,
                              hipStream_t stream) {
    const float* hidden = (const float*)d_in[0];   // fp32 [2048][4096]
    const float* Wqkv   = (const float*)d_in[1];   // fp32 [4096][6144]
    const float* Wo     = (const float*)d_in[2];   // fp32 [4096][4096]
    // d_in[3] positions == arange(SEQ); position index == s, so unused.
    float* out = (float*)d_out;                    // fp32 [2048][4096]

    char* ws = (char*)d_ws;
    float*    qkv   = (float*)   (ws);                   // 50,331,648 B fp32
    ushort_t* attnB = (ushort_t*)(ws);                   // aliases qkv (qkv dead after preps)
    ushort_t* hidB  = (ushort_t*)(ws + 50331648);        // 16,777,216 B bf16
    ushort_t* Qb    = hidB;                              // aliases hidB (dead after GEMM1)
    ushort_t* WqkvT = (ushort_t*)(ws + 67108864);        // 50,331,648 B bf16
    ushort_t* WoT   = (ushort_t*)(ws + 117440512);       // 33,554,432 B bf16
    ushort_t* Kb    = (ushort_t*)(ws + 150994944);       //  4,194,304 B bf16
    ushort_t* Vt    = (ushort_t*)(ws + 155189248);       //  4,194,304 B bf16

    f32_to_bf16<<<(S_LEN * HID) / 256, 256, 0, stream>>>(hidden, hidB);
    transpose_f32_bf16<<<dim3(QKVN / 32, HID / 32), 256, 0, stream>>>(Wqkv, WqkvT, HID, QKVN);
    transpose_f32_bf16<<<dim3(HID / 32, HID / 32), 256, 0, stream>>>(Wo, WoT, HID, HID);

    gemm_bf16<<<dim3(QKVN / 128, S_LEN / 128), 256, 0, stream>>>(
        hidB, WqkvT, qkv, S_LEN, QKVN, HID);

    prep_q<<<(NH  * S_LEN * HD) / 256, 256, 0, stream>>>(qkv, Qb);
    prep_k<<<(NKV * S_LEN * HD) / 256, 256, 0, stream>>>(qkv, Kb);
    prep_v<<<dim3(S_LEN / 32, HD / 32, NKV), 256, 0, stream>>>(qkv, Vt);

    flash_attn<<<dim3(32, NH), 256, 0, stream>>>(Qb, Kb, Vt, attnB);

    gemm_bf16<<<dim3(HID / 128, S_LEN / 128), 256, 0, stream>>>(
        attnB, WoT, out, S_LEN, HID, HID);
}

// Round 4
// 560.973 us; speedup vs baseline: 1.3607x; 1.0520x over previous
//
#include <hip/hip_runtime.h>

#define S_LEN 2048
#define HID 4096
#define NH 32
#define NKV 8
#define HD 128
#define QKVN 6144          // (32+16)*128
#define KOFF 4096          // q block size in qkv row
#define VOFF 5120          // q+k block size

typedef unsigned short ushort_t;
typedef unsigned int uint_t;
typedef __attribute__((ext_vector_type(8))) short short8;
typedef __attribute__((ext_vector_type(4))) short short4v;
typedef __attribute__((ext_vector_type(4))) float float4_t;

__device__ __forceinline__ float bf2f(ushort_t u) {
    return __uint_as_float(((uint_t)u) << 16);
}
__device__ __forceinline__ uint_t f2bf(float f) {
    uint_t u = __float_as_uint(f);
    u += 0x7fffu + ((u >> 16) & 1u);   // round-to-nearest-even
    return u >> 16;
}

// async global->LDS DMA: 16B per lane, LDS dest = wave-uniform base + lane*16
__device__ __forceinline__ void gload_lds16(const ushort_t* g, ushort_t* l) {
    __builtin_amdgcn_global_load_lds(
        (const __attribute__((address_space(1))) void*)g,
        (__attribute__((address_space(3))) void*)l, 16, 0, 0);
}

// --------------------------------------------------------- fp32 -> bf16 copy
// vectorized: 4 floats -> 4 bf16 per lane (16B in / 8B out)
__global__ void f32_to_bf16(const float4* __restrict__ in,
                            short4v* __restrict__ out) {
    int i = blockIdx.x * 256 + threadIdx.x;
    float4 v = in[i];
    short4v o;
    o[0] = (short)f2bf(v.x);
    o[1] = (short)f2bf(v.y);
    o[2] = (short)f2bf(v.z);
    o[3] = (short)f2bf(v.w);
    out[i] = o;
}

// --------------------------------------------- transpose + convert to bf16
// out[C][R] (bf16) = in[R][C] (fp32); paired-bf16 (uint) stores
__global__ void transpose_f32_bf16(const float* __restrict__ in,
                                   ushort_t* __restrict__ out, int R, int C) {
    __shared__ float t[32][33];
    int c0 = blockIdx.x * 32, r0 = blockIdx.y * 32;
    int ci = threadIdx.x & 31, rb = threadIdx.x >> 5;   // rb in [0,8)
#pragma unroll
    for (int p = 0; p < 4; p++) {
        int ri = rb + p * 8;
        t[ri][ci] = in[(size_t)(r0 + ri) * C + c0 + ci];
    }
    __syncthreads();
    int cp = (threadIdx.x & 15) * 2;     // even col of the pair
    int rw = threadIdx.x >> 4;           // 0..15
#pragma unroll
    for (int p = 0; p < 2; p++) {
        int ri = rw + p * 16;
        uint_t w = f2bf(t[cp][ri]) | (f2bf(t[cp + 1][ri]) << 16);
        *(uint_t*)(&out[(size_t)(c0 + ri) * R + r0 + cp]) = w;
    }
}

// ---------------------------------------------------------------- GEMM
// C[M][N] (fp32) = A[M][K] (bf16 row-major) * BT[N][K]^T (bf16 row-major)
// 128x128 block tile, BK=32, 4 waves, each wave 64x64 via 4x4 mfma 16x16x32.
// m97 structure: staging via global_load_lds dwordx4 (direct HBM->LDS DMA).
__global__ __launch_bounds__(256, 2)
void gemm_bf16(const ushort_t* __restrict__ A, const ushort_t* __restrict__ BT,
               float* __restrict__ Cout, int M, int N, int K) {
    __shared__ __attribute__((aligned(16))) ushort_t As[128 * 32];
    __shared__ __attribute__((aligned(16))) ushort_t Bs[128 * 32];
    const int tid  = threadIdx.x;
    const int wave = tid >> 6;
    const int lane = tid & 63;
    const int quad = lane >> 4;
    const int l16  = lane & 15;
    const int m0 = blockIdx.y * 128;
    const int n0 = blockIdx.x * 128;
    const int wm = (wave & 1) * 64;
    const int wn = (wave >> 1) * 64;

    // per-lane staging addresses (loop-invariant bases)
    const int r0 = tid >> 2;            // row handled by this lane (p=0)
    const int kc = (tid & 3) * 8;       // k-element offset within the row
    const ushort_t* gA0 = A  + (size_t)(m0 + r0)      * K + kc;
    const ushort_t* gA1 = A  + (size_t)(m0 + r0 + 64) * K + kc;
    const ushort_t* gB0 = BT + (size_t)(n0 + r0)      * K + kc;
    const ushort_t* gB1 = BT + (size_t)(n0 + r0 + 64) * K + kc;
    ushort_t* lA0 = &As[r0 * 32 + kc];          // byte off = tid*16
    ushort_t* lA1 = lA0 + 64 * 32;              // + 4096 B
    ushort_t* lB0 = &Bs[r0 * 32 + kc];
    ushort_t* lB1 = lB0 + 64 * 32;

    float4_t acc[4][4] = {};

    for (int k0 = 0; k0 < K; k0 += 32) {
        gload_lds16(gA0 + k0, lA0);
        gload_lds16(gA1 + k0, lA1);
        gload_lds16(gB0 + k0, lB0);
        gload_lds16(gB1 + k0, lB1);
        __syncthreads();

        short8 af[4], bfr[4];
#pragma unroll
        for (int i = 0; i < 4; i++)
            af[i] = *(const short8*)(&As[(wm + i * 16 + l16) * 32 + quad * 8]);
#pragma unroll
        for (int j = 0; j < 4; j++)
            bfr[j] = *(const short8*)(&Bs[(wn + j * 16 + l16) * 32 + quad * 8]);
#pragma unroll
        for (int i = 0; i < 4; i++)
#pragma unroll
            for (int j = 0; j < 4; j++)
                acc[i][j] = __builtin_amdgcn_mfma_f32_16x16x32_bf16(
                    af[i], bfr[j], acc[i][j], 0, 0, 0);
        __syncthreads();
    }

#pragma unroll
    for (int i = 0; i < 4; i++)
#pragma unroll
        for (int j = 0; j < 4; j++)
#pragma unroll
            for (int r = 0; r < 4; r++) {
                int row = m0 + wm + i * 16 + quad * 4 + r;
                int col = n0 + wn + j * 16 + l16;
                Cout[(size_t)row * N + col] = acc[i][j][r];
            }
}

// --------------------------------------------- RoPE cos/sin table (65K entries)
// tab[s*32+i] = {cos, sin}(s * theta^(-i/32)); computed once, read by preps.
__global__ void rope_tab_k(float2* __restrict__ tab) {
    int idx = blockIdx.x * 256 + threadIdx.x;  // s*32 + i
    int i = idx & 31;
    int s = idx >> 5;
    float invf = exp2f(-(float)i * (13.287712379549449f / 32.0f));
    float fr = (float)s * invf;
    float c, sn;
    sincosf(fr, &sn, &c);
    tab[idx] = make_float2(c, sn);
}

// ------------------------------------------------ prep Q (RoPE + scale + bf16)
#define QSC 0.12753102543918255f   // 128^-0.5 * log2(e)
__global__ void prep_q(const float* __restrict__ qkv, const float2* __restrict__ tab,
                       ushort_t* __restrict__ Qb) {
    int idx = blockIdx.x * 256 + threadIdx.x;   // h*S*HD + s*HD + d
    int d = idx & 127;
    int s = (idx >> 7) & 2047;
    int h = idx >> 18;
    const float* row = qkv + (size_t)s * QKVN + h * HD;
    float v;
    if (d < 64) {
        int i = d & 31;
        float2 cs = tab[(s << 5) + i];
        float x1 = row[i], x2 = row[i + 32];
        v = (d < 32) ? (x1 * cs.x - x2 * cs.y) : (x2 * cs.x + x1 * cs.y);
    } else {
        v = row[d];
    }
    Qb[idx] = (ushort_t)f2bf(v * QSC);
}

// ------------------------------------------------ prep K (RoPE + bf16 pack)
__global__ void prep_k(const float* __restrict__ qkv, const float2* __restrict__ tab,
                       ushort_t* __restrict__ Kb) {
    int idx = blockIdx.x * 256 + threadIdx.x;
    int d = idx & 127;
    int t = (idx >> 7) & 2047;
    int hk = idx >> 18;
    const float* row = qkv + (size_t)t * QKVN + KOFF + hk * HD;
    float v;
    if (d < 64) {
        int i = d & 31;
        float2 cs = tab[(t << 5) + i];
        float x1 = row[i], x2 = row[i + 32];
        v = (d < 32) ? (x1 * cs.x - x2 * cs.y) : (x2 * cs.x + x1 * cs.y);
    } else {
        v = row[d];
    }
    Kb[idx] = (ushort_t)f2bf(v);
}

// ------------------------------------------------ prep V (transpose to [d][t])
__global__ void prep_v(const float* __restrict__ qkv, ushort_t* __restrict__ Vt) {
    __shared__ float tile[32][33];
    int hk = blockIdx.z;
    int t0 = blockIdx.x * 32, d0 = blockIdx.y * 32;
    int ci = threadIdx.x & 31, rb = threadIdx.x >> 5;
#pragma unroll
    for (int p = 0; p < 4; p++) {
        int tr = rb + p * 8;
        tile[tr][ci] = qkv[(size_t)(t0 + tr) * QKVN + VOFF + hk * HD + d0 + ci];
    }
    __syncthreads();
#pragma unroll
    for (int p = 0; p < 4; p++) {
        int dr = rb + p * 8;
        Vt[((size_t)hk * HD + d0 + dr) * S_LEN + t0 + ci] = (ushort_t)f2bf(tile[ci][dr]);
    }
}

// ---------------------------------------------------------- flash attention
// v4: balanced block durations. Waves cover qt = bx + 32*wave (strided), so
// every block's loop bound is its wave-3 diagonal (~48..63 tiles, 1.3x spread
// vs 63x for the adjacent mapping in v3 -- v3's 20% occupancy was CUs idling
// behind heavy blocks). Light waves guard out ALL compute past their own
// diagonal (wave-uniform branch; barriers unconditional), costing only a
// wave slot, not pipe cycles. K/V staging stays block-cooperative via
// global_load_lds, double-buffered, one barrier per 32-step.
//   K LDS tile [32][128]: XOR-swizzled both sides (rule #21): linear LDS dest
//   + inverse-swizzled GLOBAL source granule + swizzled ds_read address.
//   V LDS tile [128][32]: inherent b128 profile, no swizzle needed.
__global__ __launch_bounds__(256, 4)
void flash_attn(const ushort_t* __restrict__ Qb, const ushort_t* __restrict__ Kb,
                const ushort_t* __restrict__ Vt, ushort_t* __restrict__ attn) {
    __shared__ __attribute__((aligned(16))) ushort_t Ks[2][32 * 128];
    __shared__ __attribute__((aligned(16))) ushort_t Vs[2][128 * 32];

    const int h    = blockIdx.y;
    const int hk   = h >> 2;                 // GQA: 4 q-heads per kv-head
    const int tid  = threadIdx.x;
    const int wave = tid >> 6;
    const int lane = tid & 63;
    const int quad = lane >> 4;
    const int l16  = lane & 15;
    const int bx   = (int)blockIdx.x;        // 0..31
    const int qt   = bx + 32 * wave;         // strided: balanced durations
    const int qw   = qt * 16;                // first q row of this wave

    const ushort_t* Qh = Qb + (size_t)h  * S_LEN * HD;
    const ushort_t* Kh = Kb + (size_t)hk * S_LEN * HD;
    const ushort_t* Vh = Vt + (size_t)hk * HD * S_LEN;

    // ---- staging maps (loop-invariant). LDS slot = tid*16B + p*4096B ----
    const int krow = tid >> 4;
    const int ksrc = ((tid & 15) ^ (krow & 7)) << 3;   // shorts, pre-swizzled
    const ushort_t* gK0 = Kh + (size_t)krow * HD + ksrc;
    const ushort_t* gK1 = Kh + (size_t)(krow + 16) * HD + ksrc;
    const int vrow = tid >> 2;
    const int vtb  = (tid & 3) << 3;                   // shorts
    const ushort_t* gV0 = Vh + (size_t)vrow * S_LEN + vtb;
    const ushort_t* gV1 = Vh + (size_t)(vrow + 64) * S_LEN + vtb;

    ushort_t* lK = &Ks[0][tid * 8];          // byte off = tid*16
    ushort_t* lV = &Vs[0][tid * 8];

#define STAGE(buf, t0)                                                        \
    do {                                                                      \
        gload_lds16(gK0 + (size_t)(t0) * HD, lK + (buf) * (32 * 128));        \
        gload_lds16(gK1 + (size_t)(t0) * HD, lK + (buf) * (32 * 128) + 2048); \
        gload_lds16(gV0 + (t0),              lV + (buf) * (128 * 32));        \
        gload_lds16(gV1 + (t0),              lV + (buf) * (128 * 32) + 2048); \
    } while (0)

    // Q fragments (loop-invariant): B[k=d][n=q], contiguous 16B loads
    short8 qf[4];
#pragma unroll
    for (int c = 0; c < 4; c++)
        qf[c] = *(const short8*)(Qh + (size_t)(qw + l16) * HD + c * 32 + quad * 8);

    float4_t oacc[8] = {};                   // O^T: 8 d-tiles of 16, col=q=l16
    float lsum = 0.f;                        // per-lane partial softmax denom
    const int s0 = (((quad * 2)     & 3) << 4) | l16;   // shuffle src lanes
    const int s1 = (((quad * 2 + 1) & 3) << 4) | l16;

    const int T0w   = qw & ~31;              // this wave's diagonal tile
    const int T0max = ((bx + 96) * 16) & ~31;   // wave-3 diagonal = loop bound
    const int kxor  = (l16 & 7) << 3;        // read-side XOR (shorts)

    STAGE(0, 0);
    __syncthreads();                         // drains vmcnt -> buf0 ready

#pragma unroll 1
    for (int t0 = 0; t0 <= T0max; t0 += 32) {
        const int cur = (t0 >> 5) & 1;
        if (t0 + 32 <= T0max) STAGE(cur ^ 1, t0 + 32);   // async, lands at barrier

        if (t0 <= T0w) {                     // wave-uniform: light waves skip
            const ushort_t* Kbuf = Ks[cur];
            const ushort_t* Vbuf = Vs[cur];

            // two S^T tiles: stA covers t0..t0+15, stB covers t0+16..t0+31
            float4_t stA = {}, stB = {};
#pragma unroll
            for (int c = 0; c < 4; c++) {
                short8 kfA = *(const short8*)(Kbuf + l16 * 128 +
                                              ((c * 32 + quad * 8) ^ kxor));
                short8 kfB = *(const short8*)(Kbuf + (16 + l16) * 128 +
                                              ((c * 32 + quad * 8) ^ kxor));
                stA = __builtin_amdgcn_mfma_f32_16x16x32_bf16(kfA, qf[c], stA, 0, 0, 0);
                stB = __builtin_amdgcn_mfma_f32_16x16x32_bf16(kfB, qf[c], stB, 0, 0, 0);
            }

            // P = 2^st (st already includes scale*log2e); mask only diagonal
            const bool maskT = (t0 == T0w);
            float pA[4], pB[4];
#pragma unroll
            for (int r = 0; r < 4; r++) {
                float eA = exp2f(stA[r]);
                float eB = exp2f(stB[r]);
                if (maskT) {
                    int tA = t0 + quad * 4 + r;
                    eA = (tA      <= qw + l16) ? eA : 0.f;
                    eB = (tA + 16 <= qw + l16) ? eB : 0.f;
                }
                pA[r] = eA; pB[r] = eB;
                lsum += eA + eB;
            }

            // P^T C-layout -> K=32 B-frag via packed-bf16 shuffles.
            uint_t a01 = f2bf(pA[0]) | (f2bf(pA[1]) << 16);
            uint_t a23 = f2bf(pA[2]) | (f2bf(pA[3]) << 16);
            uint_t b01 = f2bf(pB[0]) | (f2bf(pB[1]) << 16);
            uint_t b23 = f2bf(pB[2]) | (f2bf(pB[3]) << 16);
            uint_t A01s0 = (uint_t)__shfl((int)a01, s0);
            uint_t A23s0 = (uint_t)__shfl((int)a23, s0);
            uint_t B01s0 = (uint_t)__shfl((int)b01, s0);
            uint_t B23s0 = (uint_t)__shfl((int)b23, s0);
            uint_t A01s1 = (uint_t)__shfl((int)a01, s1);
            uint_t A23s1 = (uint_t)__shfl((int)a23, s1);
            uint_t B01s1 = (uint_t)__shfl((int)b01, s1);
            uint_t B23s1 = (uint_t)__shfl((int)b23, s1);
            uint_t w[4];
            w[0] = quad < 2 ? A01s0 : B01s0;
            w[1] = quad < 2 ? A23s0 : B23s0;
            w[2] = quad < 2 ? A01s1 : B01s1;
            w[3] = quad < 2 ? A23s1 : B23s1;
            short8 pb;
            __builtin_memcpy(&pb, w, 16);

            // O^T += V^T · P^T : A = V-frag from LDS
#pragma unroll
            for (int dt = 0; dt < 8; dt++) {
                short8 vf = *(const short8*)(Vbuf + (dt * 16 + l16) * 32 + quad * 8);
                oacc[dt] = __builtin_amdgcn_mfma_f32_16x16x32_bf16(vf, pb, oacc[dt], 0, 0, 0);
            }
        }

        __syncthreads();   // drains staging vmcnt; protects buf reuse
    }
#undef STAGE

    // epilogue: reduce l across quads (lane bits 4,5), normalize, store.
    lsum += __shfl_xor(lsum, 16);
    lsum += __shfl_xor(lsum, 32);
    float invl = 1.f / lsum;
    ushort_t* orow = attn + (size_t)(qw + l16) * (NH * HD) + h * HD;
#pragma unroll
    for (int dt = 0; dt < 8; dt++) {
        short4v wv;
#pragma unroll
        for (int r = 0; r < 4; r++)
            wv[r] = (short)f2bf(oacc[dt][r] * invl);
        *(short4v*)(orow + dt * 16 + quad * 4) = wv;
    }
}

// ---------------------------------------------------------------- launch
extern "C" void kernel_launch(void* const* d_in, const int* in_sizes, int n_in,
                              void* d_out, int out_size, void* d_ws, size_t ws_size,
                              hipStream_t stream) {
    const float* hidden = (const float*)d_in[0];   // fp32 [2048][4096]
    const float* Wqkv   = (const float*)d_in[1];   // fp32 [4096][6144]
    const float* Wo     = (const float*)d_in[2];   // fp32 [4096][4096]
    // d_in[3] positions == arange(SEQ); position index == s, so unused.
    float* out = (float*)d_out;                    // fp32 [2048][4096]

    char* ws = (char*)d_ws;
    float*    qkv   = (float*)   (ws);                   // 50,331,648 B fp32
    ushort_t* attnB = (ushort_t*)(ws);                   // aliases qkv (qkv dead after preps)
    ushort_t* hidB  = (ushort_t*)(ws + 50331648);        // 16,777,216 B bf16
    ushort_t* Qb    = hidB;                              // aliases hidB (dead after GEMM1)
    ushort_t* WqkvT = (ushort_t*)(ws + 67108864);        // 50,331,648 B bf16
    float2*   rtab  = (float2*)  (ws + 67108864);        // aliases WqkvT (dead after GEMM1)
    ushort_t* WoT   = (ushort_t*)(ws + 117440512);       // 33,554,432 B bf16
    ushort_t* Kb    = (ushort_t*)(ws + 150994944);       //  4,194,304 B bf16
    ushort_t* Vt    = (ushort_t*)(ws + 155189248);       //  4,194,304 B bf16

    f32_to_bf16<<<(S_LEN * HID) / 1024, 256, 0, stream>>>(
        (const float4*)hidden, (short4v*)hidB);
    transpose_f32_bf16<<<dim3(QKVN / 32, HID / 32), 256, 0, stream>>>(Wqkv, WqkvT, HID, QKVN);
    transpose_f32_bf16<<<dim3(HID / 32, HID / 32), 256, 0, stream>>>(Wo, WoT, HID, HID);

    gemm_bf16<<<dim3(QKVN / 128, S_LEN / 128), 256, 0, stream>>>(
        hidB, WqkvT, qkv, S_LEN, QKVN, HID);

    rope_tab_k<<<(S_LEN * 32) / 256, 256, 0, stream>>>(rtab);
    prep_q<<<(NH  * S_LEN * HD) / 256, 256, 0, stream>>>(qkv, rtab, Qb);
    prep_k<<<(NKV * S_LEN * HD) / 256, 256, 0, stream>>>(qkv, rtab, Kb);
    prep_v<<<dim3(S_LEN / 32, HD / 32, NKV), 256, 0, stream>>>(qkv, Vt);

    flash_attn<<<dim3(32, NH), 256, 0, stream>>>(Qb, Kb, Vt, attnB);

    gemm_bf16<<<dim3(HID / 128, S_LEN / 128), 256, 0, stream>>>(
        attnB, WoT, out, S_LEN, HID, HID);
}